// Round 11
// baseline (375.818 us; speedup 1.0000x reference)
//
#include <hip/hip_runtime.h>
#include <math.h>

#define C 128

typedef unsigned short u16;
typedef __attribute__((ext_vector_type(8))) short short8;
typedef __attribute__((ext_vector_type(4))) float f32x4;
typedef __attribute__((ext_vector_type(4))) u16 u16x4;

__device__ __forceinline__ float b2f(u16 u) {
    union { unsigned i; float f; } x; x.i = (unsigned)u << 16; return x.f;
}
__device__ __forceinline__ u16 f2b(float f) {
    union { float f; unsigned i; } x; x.f = f;
    unsigned r = x.i + 0x7FFFu + ((x.i >> 16) & 1u);
    return (u16)(r >> 16);
}
__device__ __forceinline__ float lrelu(float x) { return x > 0.f ? x : 0.2f * x; }

// ---------------- CSR build (edge_index arrives int32) ----------------

__global__ void hist_kernel(const int* __restrict__ ei, int E, int N,
                            int* __restrict__ count) {
    int total = E + N;
    for (int e = blockIdx.x * blockDim.x + threadIdx.x; e < total;
         e += gridDim.x * blockDim.x) {
        int d = (e < E) ? ei[E + e] : (e - E);
        if ((unsigned)d < (unsigned)N) atomicAdd(&count[d], 1);
    }
}

__global__ __launch_bounds__(1024) void scan_kernel(const int* __restrict__ count,
                                                    int* __restrict__ offs,
                                                    int* __restrict__ cursor, int N) {
    int tid = threadIdx.x, lane = tid & 63, wid = tid >> 6;   // 16 waves
    int CH = (N + 1023) >> 10;
    int base = tid * CH;
    int s = 0;
    for (int j = 0; j < CH; ++j) {
        int i = base + j;
        if (i < N) s += count[i];
    }
    int own = s;
    #pragma unroll
    for (int d = 1; d < 64; d <<= 1) {
        int v = __shfl_up(s, d);
        if (lane >= d) s += v;
    }
    __shared__ int wtot[16];
    if (lane == 63) wtot[wid] = s;
    __syncthreads();
    if (tid < 16) {
        int t = wtot[tid];
        int u = t;
        #pragma unroll
        for (int d = 1; d < 16; d <<= 1) {
            int v = __shfl_up(u, d);
            if (tid >= d) u += v;
        }
        wtot[tid] = u - t;            // exclusive wave offset
        if (tid == 15) offs[N] = u;
    }
    __syncthreads();
    int run = wtot[wid] + s - own;
    for (int j = 0; j < CH; ++j) {
        int i = base + j;
        if (i < N) {
            offs[i] = run;
            cursor[i] = run;
            run += count[i];
        }
    }
}

__global__ void scatter_kernel(const int* __restrict__ ei, int E, int N,
                               int* __restrict__ cursor, int* __restrict__ srcs,
                               int* __restrict__ dsts) {
    int total = E + N;
    for (int e = blockIdx.x * blockDim.x + threadIdx.x; e < total;
         e += gridDim.x * blockDim.x) {
        int sNode, d;
        if (e < E) { sNode = ei[e]; d = ei[E + e]; }
        else       { sNode = e - E; d = sNode; }
        if ((unsigned)d < (unsigned)N && (unsigned)sNode < (unsigned)N) {
            int pos = atomicAdd(&cursor[d], 1);
            srcs[pos] = sNode;
            dsts[pos] = d;
        }
    }
}

// Wc[l][o][h*128+i] = 0.25 * Wl[h][i][o]  (head-mean folded; [128 cols][512 k] bf16)
__global__ __launch_bounds__(128) void cvt_w_kernel(const float* __restrict__ W1,
                                                    const float* __restrict__ Wr,
                                                    const float* __restrict__ W2,
                                                    u16* __restrict__ Wc) {
    int b = blockIdx.x;            // 0..383
    int l = b >> 7, o = b & 127;
    const float* W = (l == 0) ? W1 : (l == 1) ? Wr : W2;
    int i = threadIdx.x;
    u16* dst = Wc + ((size_t)l * C + o) * 512;
    #pragma unroll
    for (int h = 0; h < 4; ++h) {
        dst[h * C + i] = f2b(0.25f * W[((size_t)h * C + i) * C + o]);
    }
}

// ---------------- W@a vectors -> bf16 B-matrices for the al MFMA kernels ----------

__global__ __launch_bounds__(256) void wvec_kernel(const float* __restrict__ W1,
                                                   const float* __restrict__ as1,
                                                   const float* __restrict__ ad1,
                                                   const float* __restrict__ Wr,
                                                   const float* __restrict__ asr,
                                                   const float* __restrict__ adr,
                                                   const float* __restrict__ W2,
                                                   const float* __restrict__ as2,
                                                   const float* __restrict__ ad2,
                                                   u16* __restrict__ vsdA,
                                                   u16* __restrict__ vsdB) {
    int slot = blockIdx.x;        // 0..11
    const float* W  = (slot < 4) ? W1 : (slot < 8) ? Wr : W2;
    const float* s_ = (slot < 4) ? as1 : (slot < 8) ? asr : as2;
    const float* d_ = (slot < 4) ? ad1 : (slot < 8) ? adr : ad2;
    int h = slot & 3;
    int wave = threadIdx.x >> 6, lane = threadIdx.x & 63;
    int rbase = blockIdx.y * 32 + wave * 8;
    float as0 = s_[h * C + lane], as1v = s_[h * C + 64 + lane];
    float ad0 = d_[h * C + lane], ad1v = d_[h * C + 64 + lane];
    #pragma unroll
    for (int j = 0; j < 8; ++j) {
        int i = rbase + j;
        const float* Wrow = W + ((size_t)h * C + i) * C;
        float w0 = Wrow[lane], w1 = Wrow[64 + lane];
        float ps = w0 * as0 + w1 * as1v;
        float pd = w0 * ad0 + w1 * ad1v;
        #pragma unroll
        for (int m = 32; m; m >>= 1) {
            ps += __shfl_xor(ps, m);
            pd += __shfl_xor(pd, m);
        }
        if (lane == 0) {
            if (slot < 8) {
                vsdA[slot * C + i] = f2b(ps);
                vsdA[(8 + slot) * C + i] = f2b(pd);
            } else {
                vsdB[(slot - 8) * C + i] = f2b(ps);
                vsdB[(4 + (slot - 8)) * C + i] = f2b(pd);
            }
        }
    }
}

// ---------------- group-A logits via MFMA, fused with x fp32->bf16 ----------------

__global__ __launch_bounds__(256) void alA_kernel(const float* __restrict__ x,
                                                  const u16* __restrict__ vsd,
                                                  u16* __restrict__ xb,
                                                  float* __restrict__ als,
                                                  float* __restrict__ ald, int N) {
    int wave = threadIdx.x >> 6, lane = threadIdx.x & 63;
    int rowBase = blockIdx.x * 64 + wave * 16;
    int r = rowBase + (lane & 15);
    int rl = r < N ? r : N - 1;
    int kg = (lane >> 4) * 8;

    short8 a[4];
    #pragma unroll
    for (int t = 0; t < 4; ++t) {
        const float* xp = x + (size_t)rl * C + t * 32 + kg;
        float4 f0 = *(const float4*)xp;
        float4 f1 = *(const float4*)(xp + 4);
        short8 s;
        s[0] = f2b(f0.x); s[1] = f2b(f0.y); s[2] = f2b(f0.z); s[3] = f2b(f0.w);
        s[4] = f2b(f1.x); s[5] = f2b(f1.y); s[6] = f2b(f1.z); s[7] = f2b(f1.w);
        a[t] = s;
        if (r < N) *(short8*)(xb + (size_t)r * C + t * 32 + kg) = s;
    }
    f32x4 acc = {0.f, 0.f, 0.f, 0.f};
    int col = lane & 15;
    #pragma unroll
    for (int t = 0; t < 4; ++t) {
        short8 b = *(const short8*)(vsd + (size_t)col * C + t * 32 + kg);
        acc = __builtin_amdgcn_mfma_f32_16x16x32_bf16(a[t], b, acc, 0, 0, 0);
    }
    #pragma unroll
    for (int j = 0; j < 4; ++j) {
        int rr = rowBase + (lane >> 4) * 4 + j;
        if (rr < N) {
            if (col < 8) als[rr * 8 + col] = acc[j];
            else ald[rr * 8 + (col - 8)] = acc[j];
        }
    }
}

// ---------------- group-B logits via MFMA (h1b bf16 input) ----------------

__global__ __launch_bounds__(256) void alB_kernel(const u16* __restrict__ in,
                                                  const u16* __restrict__ vsd,
                                                  float* __restrict__ als,
                                                  float* __restrict__ ald, int N) {
    int wave = threadIdx.x >> 6, lane = threadIdx.x & 63;
    int rowBase = blockIdx.x * 64 + wave * 16;
    int r = rowBase + (lane & 15);
    int rl = r < N ? r : N - 1;
    int kg = (lane >> 4) * 8;

    f32x4 acc = {0.f, 0.f, 0.f, 0.f};
    int col = lane & 15;
    #pragma unroll
    for (int t = 0; t < 4; ++t) {
        short8 a = *(const short8*)(in + (size_t)rl * C + t * 32 + kg);
        short8 b = *(const short8*)(vsd + (size_t)col * C + t * 32 + kg);
        acc = __builtin_amdgcn_mfma_f32_16x16x32_bf16(a, b, acc, 0, 0, 0);
    }
    #pragma unroll
    for (int j = 0; j < 4; ++j) {
        int rr = rowBase + (lane >> 4) * 4 + j;
        if (rr < N && col < 8) {
            if (col < 4) als[rr * 4 + col] = acc[j];
            else ald[rr * 4 + (col - 4)] = acc[j];
        }
    }
}

// ---------------- edge-parallel unnormalized weights (no atomics) ----------------

template <int NH>
__global__ __launch_bounds__(256) void ew_kernel(const float* __restrict__ als,
                                                 const float* __restrict__ ald,
                                                 const int* __restrict__ srcs,
                                                 const int* __restrict__ dsts,
                                                 float* __restrict__ wout, int ET) {
    int i = blockIdx.x * blockDim.x + threadIdx.x;
    if (i >= ET) return;
    int s = srcs[i], d = dsts[i];
    const float* as_ = als + (size_t)s * NH;
    const float* ad_ = ald + (size_t)d * NH;
    float* wo = wout + (size_t)i * NH;
    #pragma unroll
    for (int h = 0; h < NH; ++h) {
        wo[h] = __expf(lrelu(as_[h] + ad_[h]));
    }
}

// ---------------- node-parallel denominators: den[n][h] = sum_seg wgt[i][h] --------

template <int NH>
__global__ __launch_bounds__(256) void den_kernel(const float* __restrict__ wgt,
                                                  const int* __restrict__ offs,
                                                  float* __restrict__ den, int N) {
    int idx = blockIdx.x * blockDim.x + threadIdx.x;
    int node = idx / NH, h = idx % NH;
    if (node >= N) return;
    int beg = offs[node], end = offs[node + 1];
    float s = 0.f;
    for (int i = beg; i < end; ++i) s += wgt[(size_t)i * NH + h];
    den[idx] = s;
}

// ---------------- aggregation: dest[n][h*128+c] = (1/den[n,h]) * sum w[e,h]*xsrc[c] --

template <int NH>
__global__ __launch_bounds__(256) void aggx_kernel(const u16* __restrict__ xsrc,
                                                   const float* __restrict__ wgt,
                                                   const float* __restrict__ den,
                                                   const int* __restrict__ offs,
                                                   const int* __restrict__ srcs,
                                                   u16* __restrict__ dest, int N) {
    constexpr int NHG = NH / 2;
    int node = blockIdx.x * 4 + (threadIdx.x >> 6);
    int lane = threadIdx.x & 63;
    if (node >= N) return;
    int g = lane >> 5;
    int c0 = (lane & 31) * 4;
    int beg = offs[node], end = offs[node + 1];

    float inv[NHG];
    #pragma unroll
    for (int j = 0; j < NHG; ++j) {
        inv[j] = 1.f / den[(size_t)node * NH + g * NHG + j];
    }

    float acc[NHG][4] = {};
    int i = beg;
    for (; i + 8 <= end; i += 8) {
        int s[8];
        #pragma unroll
        for (int e = 0; e < 8; ++e) s[e] = srcs[i + e];
        u16x4 v[8];
        #pragma unroll
        for (int e = 0; e < 8; ++e) {
            v[e] = *(const u16x4*)(xsrc + (size_t)s[e] * C + c0);
        }
        float wv[8][NHG];
        #pragma unroll
        for (int e = 0; e < 8; ++e) {
            if constexpr (NHG == 4) {
                float4 wq = *(const float4*)(wgt + (size_t)(i + e) * NH + g * NHG);
                wv[e][0] = wq.x; wv[e][1] = wq.y; wv[e][2] = wq.z; wv[e][3] = wq.w;
            } else {
                float2 wq = *(const float2*)(wgt + (size_t)(i + e) * NH + g * NHG);
                wv[e][0] = wq.x; wv[e][1] = wq.y;
            }
        }
        #pragma unroll
        for (int e = 0; e < 8; ++e) {
            float f[4];
            #pragma unroll
            for (int j = 0; j < 4; ++j) f[j] = b2f(v[e][j]);
            #pragma unroll
            for (int j2 = 0; j2 < NHG; ++j2) {
                #pragma unroll
                for (int j = 0; j < 4; ++j) acc[j2][j] += wv[e][j2] * f[j];
            }
        }
    }
    for (; i < end; ++i) {
        int s0 = srcs[i];
        u16x4 v0 = *(const u16x4*)(xsrc + (size_t)s0 * C + c0);
        float w0[NHG];
        #pragma unroll
        for (int j2 = 0; j2 < NHG; ++j2) {
            w0[j2] = wgt[(size_t)i * NH + g * NHG + j2];
        }
        float f[4];
        #pragma unroll
        for (int j = 0; j < 4; ++j) f[j] = b2f(v0[j]);
        #pragma unroll
        for (int j2 = 0; j2 < NHG; ++j2) {
            #pragma unroll
            for (int j = 0; j < 4; ++j) acc[j2][j] += w0[j2] * f[j];
        }
    }

    #pragma unroll
    for (int j2 = 0; j2 < NHG; ++j2) {
        int h = g * NHG + j2;
        u16x4 o = {f2b(acc[j2][0] * inv[j2]), f2b(acc[j2][1] * inv[j2]),
                   f2b(acc[j2][2] * inv[j2]), f2b(acc[j2][3] * inv[j2])};
        *(u16x4*)(dest + (size_t)node * (NH * C) + h * C + c0) = o;
    }
}

// ---------------- post-GEMM A+B: kk-outer loop, single live A-frag (no spill) ------

__global__ __launch_bounds__(256) void gemm2ab_kernel(const u16* __restrict__ agg,
                                                      const u16* __restrict__ Wc,
                                                      const float* __restrict__ b1,
                                                      const float* __restrict__ br,
                                                      u16* __restrict__ h1b,
                                                      float* __restrict__ outf, int N) {
    int part = blockIdx.y;
    const u16* A = agg + part * 512;
    const u16* W = Wc + (size_t)part * C * 512;
    const float* bias = part ? br : b1;

    int wave = threadIdx.x >> 6, lane = threadIdx.x & 63;
    int rowBase = blockIdx.x * 64 + wave * 16;
    int r = rowBase + (lane & 15);
    int rl = r < N ? r : N - 1;
    int kg = (lane >> 4) * 8;

    const short8* ap = (const short8*)(A + (size_t)rl * 1024 + kg);
    const short8* bp = (const short8*)(W + (size_t)(lane & 15) * 512 + kg);

    f32x4 acc[8];
    #pragma unroll
    for (int t = 0; t < 8; ++t) acc[t] = (f32x4){0.f, 0.f, 0.f, 0.f};

    #pragma unroll
    for (int kk = 0; kk < 16; ++kk) {
        short8 a = ap[kk * 4];
        #pragma unroll
        for (int t = 0; t < 8; ++t) {
            acc[t] = __builtin_amdgcn_mfma_f32_16x16x32_bf16(
                a, bp[(size_t)t * 16 * 64 + kk * 4], acc[t], 0, 0, 0);
        }
    }

    int prow = rowBase + (lane >> 4) * 4;
    #pragma unroll
    for (int t = 0; t < 8; ++t) {
        int col = t * 16 + (lane & 15);
        float bcol = bias[col];
        #pragma unroll
        for (int j = 0; j < 4; ++j) {
            int rr = prow + j;
            if (rr < N) {
                float v = acc[t][j] + bcol;
                if (part == 0) h1b[(size_t)rr * C + col] = f2b(v);
                else outf[(size_t)rr * C + col] = v;
            }
        }
    }
}

// ---------------- layer-2 post-GEMM: out += A @ Wc2^T + b2 (kk-outer) --------------

__global__ __launch_bounds__(256) void gemm2c_kernel(const u16* __restrict__ A,
                                                     const u16* __restrict__ Wc,
                                                     const float* __restrict__ bias,
                                                     float* __restrict__ outf, int N) {
    int wave = threadIdx.x >> 6, lane = threadIdx.x & 63;
    int rowBase = blockIdx.x * 64 + wave * 16;
    int r = rowBase + (lane & 15);
    int rl = r < N ? r : N - 1;
    int kg = (lane >> 4) * 8;

    const short8* ap = (const short8*)(A + (size_t)rl * 512 + kg);
    const short8* bp = (const short8*)(Wc + (size_t)(lane & 15) * 512 + kg);

    f32x4 acc[8];
    #pragma unroll
    for (int t = 0; t < 8; ++t) acc[t] = (f32x4){0.f, 0.f, 0.f, 0.f};

    #pragma unroll
    for (int kk = 0; kk < 16; ++kk) {
        short8 a = ap[kk * 4];
        #pragma unroll
        for (int t = 0; t < 8; ++t) {
            acc[t] = __builtin_amdgcn_mfma_f32_16x16x32_bf16(
                a, bp[(size_t)t * 16 * 64 + kk * 4], acc[t], 0, 0, 0);
        }
    }

    int prow = rowBase + (lane >> 4) * 4;
    #pragma unroll
    for (int t = 0; t < 8; ++t) {
        int col = t * 16 + (lane & 15);
        float bcol = bias[col];
        #pragma unroll
        for (int j = 0; j < 4; ++j) {
            int rr = prow + j;
            if (rr < N) outf[(size_t)rr * C + col] += acc[t][j] + bcol;
        }
    }
}

// ---------------- launch ----------------

extern "C" void kernel_launch(void* const* d_in, const int* in_sizes, int n_in,
                              void* d_out, int out_size, void* d_ws, size_t ws_size,
                              hipStream_t stream) {
    const float* x = (const float*)d_in[0];
    const int* ei = (const int*)d_in[1];
    const float* W1 = (const float*)d_in[2];
    const float* as1 = (const float*)d_in[3];
    const float* ad1 = (const float*)d_in[4];
    const float* b1 = (const float*)d_in[5];
    const float* W2 = (const float*)d_in[6];
    const float* as2 = (const float*)d_in[7];
    const float* ad2 = (const float*)d_in[8];
    const float* b2 = (const float*)d_in[9];
    const float* Wr = (const float*)d_in[10];
    const float* asr = (const float*)d_in[11];
    const float* adr = (const float*)d_in[12];
    const float* br = (const float*)d_in[13];

    int N = in_sizes[0] / C;   // 20000
    int E = in_sizes[1] / 2;   // 320000
    int ET = E + N;

    size_t sz_xb    = (size_t)N * C * 2;
    size_t sz_h1b   = (size_t)N * C * 2;
    size_t sz_aggA  = (size_t)N * 1024 * 2;
    size_t sz_aggB  = (size_t)N * 512 * 2;
    size_t sz_wc    = (size_t)3 * C * 512 * 2;
    size_t sz_vsd   = (size_t)16 * C * 2;
    size_t sz_al8   = (size_t)N * 8 * 4;
    size_t sz_count = (size_t)N * 4;
    size_t sz_den8  = (size_t)N * 8 * 4;
    size_t sz_den4  = (size_t)N * 4 * 4;
    size_t sz_offs  = (size_t)(N + 4) * 4;
    size_t sz_srcs  = (size_t)ET * 4;
    size_t sz_w     = (size_t)ET * 8 * 4;
    size_t required = sz_xb + sz_h1b + sz_aggA + sz_aggB + sz_wc + 2 * sz_vsd +
                      2 * sz_al8 + sz_count + sz_den8 + sz_den4 + sz_count +
                      sz_offs + 2 * sz_srcs + sz_w;
    if (ws_size < required) return;

    char* w = (char*)d_ws;
    u16* xb = (u16*)w;        w += sz_xb;
    u16* h1b = (u16*)w;       w += sz_h1b;
    u16* aggA = (u16*)w;      w += sz_aggA;
    u16* aggB = (u16*)w;      w += sz_aggB;
    u16* Wc = (u16*)w;        w += sz_wc;
    u16* vsdA = (u16*)w;      w += sz_vsd;
    u16* vsdB = (u16*)w;      w += sz_vsd;
    float* als = (float*)w;   w += sz_al8;
    float* ald = (float*)w;   w += sz_al8;
    int* count = (int*)w;     w += sz_count;
    float* den8 = (float*)w;  w += sz_den8;
    float* den4 = (float*)w;  w += sz_den4;
    int* cursor = (int*)w;    w += sz_count;
    int* offs = (int*)w;      w += sz_offs;
    int* srcs = (int*)w;      w += sz_srcs;
    int* dsts = (int*)w;      w += sz_srcs;
    float* wgt = (float*)w;   w += sz_w;
    float* out = (float*)d_out;

    const u16* Wc2 = Wc + (size_t)2 * C * 512;

    hipMemsetAsync(count, 0, sz_count, stream);
    hist_kernel<<<512, 256, 0, stream>>>(ei, E, N, count);
    scan_kernel<<<1, 1024, 0, stream>>>(count, offs, cursor, N);
    scatter_kernel<<<512, 256, 0, stream>>>(ei, E, N, cursor, srcs, dsts);

    cvt_w_kernel<<<384, 128, 0, stream>>>(W1, Wr, W2, Wc);
    wvec_kernel<<<dim3(12, 4), 256, 0, stream>>>(W1, as1, ad1, Wr, asr, adr,
                                                 W2, as2, ad2, vsdA, vsdB);

    int nwb = (N + 3) / 4;
    int neb = (ET + 255) / 256;
    int gx = (N + 63) / 64;
    int nd8 = (N * 8 + 255) / 256;
    int nd4 = (N * 4 + 255) / 256;

    // group A: layer1 + residual (share the x gather)
    alA_kernel<<<gx, 256, 0, stream>>>(x, vsdA, xb, als, ald, N);
    ew_kernel<8><<<neb, 256, 0, stream>>>(als, ald, srcs, dsts, wgt, ET);
    den_kernel<8><<<nd8, 256, 0, stream>>>(wgt, offs, den8, N);
    aggx_kernel<8><<<nwb, 256, 0, stream>>>(xb, wgt, den8, offs, srcs, aggA, N);
    gemm2ab_kernel<<<dim3(gx, 2), 256, 0, stream>>>(aggA, Wc, b1, br, h1b, out, N);

    // group B: layer2
    alB_kernel<<<gx, 256, 0, stream>>>(h1b, vsdB, als, ald, N);
    ew_kernel<4><<<neb, 256, 0, stream>>>(als, ald, srcs, dsts, wgt, ET);
    den_kernel<4><<<nd4, 256, 0, stream>>>(wgt, offs, den4, N);
    aggx_kernel<4><<<nwb, 256, 0, stream>>>(h1b, wgt, den4, offs, srcs, aggB, N);
    gemm2c_kernel<<<gx, 256, 0, stream>>>(aggB, Wc2, b2, out, N);
}

// Round 12
// 365.916 us; speedup vs baseline: 1.0271x; 1.0271x over previous
//
#include <hip/hip_runtime.h>
#include <math.h>

#define C 128

typedef unsigned short u16;
typedef __attribute__((ext_vector_type(8))) short short8;
typedef __attribute__((ext_vector_type(4))) float f32x4;
typedef __attribute__((ext_vector_type(4))) u16 u16x4;

__device__ __forceinline__ float b2f(u16 u) {
    union { unsigned i; float f; } x; x.i = (unsigned)u << 16; return x.f;
}
__device__ __forceinline__ u16 f2b(float f) {
    union { float f; unsigned i; } x; x.f = f;
    unsigned r = x.i + 0x7FFFu + ((x.i >> 16) & 1u);
    return (u16)(r >> 16);
}
__device__ __forceinline__ float lrelu(float x) { return x > 0.f ? x : 0.2f * x; }

// ---------------- CSR build (edge_index arrives int32) ----------------

__global__ void hist_kernel(const int* __restrict__ ei, int E, int N,
                            int* __restrict__ count) {
    int total = E + N;
    for (int e = blockIdx.x * blockDim.x + threadIdx.x; e < total;
         e += gridDim.x * blockDim.x) {
        int d = (e < E) ? ei[E + e] : (e - E);
        if ((unsigned)d < (unsigned)N) atomicAdd(&count[d], 1);
    }
}

__global__ __launch_bounds__(1024) void scan_kernel(const int* __restrict__ count,
                                                    int* __restrict__ offs,
                                                    int* __restrict__ cursor, int N) {
    int tid = threadIdx.x, lane = tid & 63, wid = tid >> 6;   // 16 waves
    int CH = (N + 1023) >> 10;
    int base = tid * CH;
    int s = 0;
    for (int j = 0; j < CH; ++j) {
        int i = base + j;
        if (i < N) s += count[i];
    }
    int own = s;
    #pragma unroll
    for (int d = 1; d < 64; d <<= 1) {
        int v = __shfl_up(s, d);
        if (lane >= d) s += v;
    }
    __shared__ int wtot[16];
    if (lane == 63) wtot[wid] = s;
    __syncthreads();
    if (tid < 16) {
        int t = wtot[tid];
        int u = t;
        #pragma unroll
        for (int d = 1; d < 16; d <<= 1) {
            int v = __shfl_up(u, d);
            if (tid >= d) u += v;
        }
        wtot[tid] = u - t;            // exclusive wave offset
        if (tid == 15) offs[N] = u;
    }
    __syncthreads();
    int run = wtot[wid] + s - own;
    for (int j = 0; j < CH; ++j) {
        int i = base + j;
        if (i < N) {
            offs[i] = run;
            cursor[i] = run;
            run += count[i];
        }
    }
}

__global__ void scatter_kernel(const int* __restrict__ ei, int E, int N,
                               int* __restrict__ cursor, int* __restrict__ srcs,
                               int* __restrict__ dsts) {
    int total = E + N;
    for (int e = blockIdx.x * blockDim.x + threadIdx.x; e < total;
         e += gridDim.x * blockDim.x) {
        int sNode, d;
        if (e < E) { sNode = ei[e]; d = ei[E + e]; }
        else       { sNode = e - E; d = sNode; }
        if ((unsigned)d < (unsigned)N && (unsigned)sNode < (unsigned)N) {
            int pos = atomicAdd(&cursor[d], 1);
            srcs[pos] = sNode;
            dsts[pos] = d;
        }
    }
}

// ---------------- W -> MFMA-fragment layout ----------------
// Wf[((l*8 + t)*16 + kk)*512 + lane*8 + j] = 0.25*W_l[h][i][o]
// with o = t*16 + (lane&15), khi = kk*32 + (lane>>4)*8 + j, h = khi>>7, i = khi&127.
// A wave's B-load for (l,t,kk) is then one coalesced 1 KB transaction.

__global__ __launch_bounds__(256) void cvt_w_kernel(const float* __restrict__ W1,
                                                    const float* __restrict__ Wr,
                                                    const float* __restrict__ W2,
                                                    u16* __restrict__ Wf) {
    int idx = blockIdx.x * 256 + threadIdx.x;   // 24576 groups total
    int lane = idx & 63;
    int kk = (idx >> 6) & 15;
    int t = (idx >> 10) & 7;
    int l = idx >> 13;
    if (l >= 3) return;
    const float* W = (l == 0) ? W1 : (l == 1) ? Wr : W2;
    int o = t * 16 + (lane & 15);
    int bk = kk * 32 + (lane >> 4) * 8;
    int h = bk >> 7, i0 = bk & 127;
    short8 v;
    #pragma unroll
    for (int j = 0; j < 8; ++j) {
        v[j] = (short)f2b(0.25f * W[((size_t)h * C + i0 + j) * C + o]);
    }
    *(short8*)(Wf + (size_t)idx * 8) = v;
}

// ---------------- W@a vectors -> bf16 B-matrices for the al MFMA kernels ----------

__global__ __launch_bounds__(256) void wvec_kernel(const float* __restrict__ W1,
                                                   const float* __restrict__ as1,
                                                   const float* __restrict__ ad1,
                                                   const float* __restrict__ Wr,
                                                   const float* __restrict__ asr,
                                                   const float* __restrict__ adr,
                                                   const float* __restrict__ W2,
                                                   const float* __restrict__ as2,
                                                   const float* __restrict__ ad2,
                                                   u16* __restrict__ vsdA,
                                                   u16* __restrict__ vsdB) {
    int slot = blockIdx.x;        // 0..11
    const float* W  = (slot < 4) ? W1 : (slot < 8) ? Wr : W2;
    const float* s_ = (slot < 4) ? as1 : (slot < 8) ? asr : as2;
    const float* d_ = (slot < 4) ? ad1 : (slot < 8) ? adr : ad2;
    int h = slot & 3;
    int wave = threadIdx.x >> 6, lane = threadIdx.x & 63;
    int rbase = blockIdx.y * 32 + wave * 8;
    float as0 = s_[h * C + lane], as1v = s_[h * C + 64 + lane];
    float ad0 = d_[h * C + lane], ad1v = d_[h * C + 64 + lane];
    #pragma unroll
    for (int j = 0; j < 8; ++j) {
        int i = rbase + j;
        const float* Wrow = W + ((size_t)h * C + i) * C;
        float w0 = Wrow[lane], w1 = Wrow[64 + lane];
        float ps = w0 * as0 + w1 * as1v;
        float pd = w0 * ad0 + w1 * ad1v;
        #pragma unroll
        for (int m = 32; m; m >>= 1) {
            ps += __shfl_xor(ps, m);
            pd += __shfl_xor(pd, m);
        }
        if (lane == 0) {
            if (slot < 8) {
                vsdA[slot * C + i] = f2b(ps);
                vsdA[(8 + slot) * C + i] = f2b(pd);
            } else {
                vsdB[(slot - 8) * C + i] = f2b(ps);
                vsdB[(4 + (slot - 8)) * C + i] = f2b(pd);
            }
        }
    }
}

// ---------------- group-A logits via MFMA, fused with x fp32->bf16 ----------------

__global__ __launch_bounds__(256) void alA_kernel(const float* __restrict__ x,
                                                  const u16* __restrict__ vsd,
                                                  u16* __restrict__ xb,
                                                  float* __restrict__ als,
                                                  float* __restrict__ ald, int N) {
    int wave = threadIdx.x >> 6, lane = threadIdx.x & 63;
    int rowBase = blockIdx.x * 64 + wave * 16;
    int r = rowBase + (lane & 15);
    int rl = r < N ? r : N - 1;
    int kg = (lane >> 4) * 8;

    short8 a[4];
    #pragma unroll
    for (int t = 0; t < 4; ++t) {
        const float* xp = x + (size_t)rl * C + t * 32 + kg;
        float4 f0 = *(const float4*)xp;
        float4 f1 = *(const float4*)(xp + 4);
        short8 s;
        s[0] = f2b(f0.x); s[1] = f2b(f0.y); s[2] = f2b(f0.z); s[3] = f2b(f0.w);
        s[4] = f2b(f1.x); s[5] = f2b(f1.y); s[6] = f2b(f1.z); s[7] = f2b(f1.w);
        a[t] = s;
        if (r < N) *(short8*)(xb + (size_t)r * C + t * 32 + kg) = s;
    }
    f32x4 acc = {0.f, 0.f, 0.f, 0.f};
    int col = lane & 15;
    #pragma unroll
    for (int t = 0; t < 4; ++t) {
        short8 b = *(const short8*)(vsd + (size_t)col * C + t * 32 + kg);
        acc = __builtin_amdgcn_mfma_f32_16x16x32_bf16(a[t], b, acc, 0, 0, 0);
    }
    #pragma unroll
    for (int j = 0; j < 4; ++j) {
        int rr = rowBase + (lane >> 4) * 4 + j;
        if (rr < N) {
            if (col < 8) als[rr * 8 + col] = acc[j];
            else ald[rr * 8 + (col - 8)] = acc[j];
        }
    }
}

// ---------------- group-B logits via MFMA (h1b bf16 input) ----------------

__global__ __launch_bounds__(256) void alB_kernel(const u16* __restrict__ in,
                                                  const u16* __restrict__ vsd,
                                                  float* __restrict__ als,
                                                  float* __restrict__ ald, int N) {
    int wave = threadIdx.x >> 6, lane = threadIdx.x & 63;
    int rowBase = blockIdx.x * 64 + wave * 16;
    int r = rowBase + (lane & 15);
    int rl = r < N ? r : N - 1;
    int kg = (lane >> 4) * 8;

    f32x4 acc = {0.f, 0.f, 0.f, 0.f};
    int col = lane & 15;
    #pragma unroll
    for (int t = 0; t < 4; ++t) {
        short8 a = *(const short8*)(in + (size_t)rl * C + t * 32 + kg);
        short8 b = *(const short8*)(vsd + (size_t)col * C + t * 32 + kg);
        acc = __builtin_amdgcn_mfma_f32_16x16x32_bf16(a, b, acc, 0, 0, 0);
    }
    #pragma unroll
    for (int j = 0; j < 4; ++j) {
        int rr = rowBase + (lane >> 4) * 4 + j;
        if (rr < N && col < 8) {
            if (col < 4) als[rr * 4 + col] = acc[j];
            else ald[rr * 4 + (col - 4)] = acc[j];
        }
    }
}

// ---------------- edge-parallel unnormalized weights (no atomics) ----------------

template <int NH>
__global__ __launch_bounds__(256) void ew_kernel(const float* __restrict__ als,
                                                 const float* __restrict__ ald,
                                                 const int* __restrict__ srcs,
                                                 const int* __restrict__ dsts,
                                                 float* __restrict__ wout, int ET) {
    int i = blockIdx.x * blockDim.x + threadIdx.x;
    if (i >= ET) return;
    int s = srcs[i], d = dsts[i];
    const float* as_ = als + (size_t)s * NH;
    const float* ad_ = ald + (size_t)d * NH;
    float* wo = wout + (size_t)i * NH;
    #pragma unroll
    for (int h = 0; h < NH; ++h) {
        wo[h] = __expf(lrelu(as_[h] + ad_[h]));
    }
}

// ---------------- node-parallel denominators: den[n][h] = sum_seg wgt[i][h] --------

template <int NH>
__global__ __launch_bounds__(256) void den_kernel(const float* __restrict__ wgt,
                                                  const int* __restrict__ offs,
                                                  float* __restrict__ den, int N) {
    int idx = blockIdx.x * blockDim.x + threadIdx.x;
    int node = idx / NH, h = idx % NH;
    if (node >= N) return;
    int beg = offs[node], end = offs[node + 1];
    float s = 0.f;
    for (int i = beg; i < end; ++i) s += wgt[(size_t)i * NH + h];
    den[idx] = s;
}

// ---------------- aggregation: dest[n][h*128+c] = (1/den[n,h]) * sum w[e,h]*xsrc[c] --

template <int NH>
__global__ __launch_bounds__(256) void aggx_kernel(const u16* __restrict__ xsrc,
                                                   const float* __restrict__ wgt,
                                                   const float* __restrict__ den,
                                                   const int* __restrict__ offs,
                                                   const int* __restrict__ srcs,
                                                   u16* __restrict__ dest, int N) {
    constexpr int NHG = NH / 2;
    int node = blockIdx.x * 4 + (threadIdx.x >> 6);
    int lane = threadIdx.x & 63;
    if (node >= N) return;
    int g = lane >> 5;
    int c0 = (lane & 31) * 4;
    int beg = offs[node], end = offs[node + 1];

    float inv[NHG];
    #pragma unroll
    for (int j = 0; j < NHG; ++j) {
        inv[j] = 1.f / den[(size_t)node * NH + g * NHG + j];
    }

    float acc[NHG][4] = {};
    int i = beg;
    for (; i + 8 <= end; i += 8) {
        int s[8];
        #pragma unroll
        for (int e = 0; e < 8; ++e) s[e] = srcs[i + e];
        u16x4 v[8];
        #pragma unroll
        for (int e = 0; e < 8; ++e) {
            v[e] = *(const u16x4*)(xsrc + (size_t)s[e] * C + c0);
        }
        float wv[8][NHG];
        #pragma unroll
        for (int e = 0; e < 8; ++e) {
            if constexpr (NHG == 4) {
                float4 wq = *(const float4*)(wgt + (size_t)(i + e) * NH + g * NHG);
                wv[e][0] = wq.x; wv[e][1] = wq.y; wv[e][2] = wq.z; wv[e][3] = wq.w;
            } else {
                float2 wq = *(const float2*)(wgt + (size_t)(i + e) * NH + g * NHG);
                wv[e][0] = wq.x; wv[e][1] = wq.y;
            }
        }
        #pragma unroll
        for (int e = 0; e < 8; ++e) {
            float f[4];
            #pragma unroll
            for (int j = 0; j < 4; ++j) f[j] = b2f(v[e][j]);
            #pragma unroll
            for (int j2 = 0; j2 < NHG; ++j2) {
                #pragma unroll
                for (int j = 0; j < 4; ++j) acc[j2][j] += wv[e][j2] * f[j];
            }
        }
    }
    for (; i < end; ++i) {
        int s0 = srcs[i];
        u16x4 v0 = *(const u16x4*)(xsrc + (size_t)s0 * C + c0);
        float w0[NHG];
        #pragma unroll
        for (int j2 = 0; j2 < NHG; ++j2) {
            w0[j2] = wgt[(size_t)i * NH + g * NHG + j2];
        }
        float f[4];
        #pragma unroll
        for (int j = 0; j < 4; ++j) f[j] = b2f(v0[j]);
        #pragma unroll
        for (int j2 = 0; j2 < NHG; ++j2) {
            #pragma unroll
            for (int j = 0; j < 4; ++j) acc[j2][j] += w0[j2] * f[j];
        }
    }

    #pragma unroll
    for (int j2 = 0; j2 < NHG; ++j2) {
        int h = g * NHG + j2;
        u16x4 o = {f2b(acc[j2][0] * inv[j2]), f2b(acc[j2][1] * inv[j2]),
                   f2b(acc[j2][2] * inv[j2]), f2b(acc[j2][3] * inv[j2])};
        *(u16x4*)(dest + (size_t)node * (NH * C) + h * C + c0) = o;
    }
}

// ---------------- post-GEMM A+B: frag-layout B (coalesced), 32 rows/wave ------------
// part 0: layer1 -> h1b bf16; part 1: residual -> out f32.

__global__ __launch_bounds__(256) void gemm2ab_kernel(const u16* __restrict__ agg,
                                                      const u16* __restrict__ Wf,
                                                      const float* __restrict__ b1,
                                                      const float* __restrict__ br,
                                                      u16* __restrict__ h1b,
                                                      float* __restrict__ outf, int N) {
    int part = blockIdx.y;
    const float* bias = part ? br : b1;
    int wave = threadIdx.x >> 6, lane = threadIdx.x & 63;
    int rowBase = blockIdx.x * 128 + wave * 32;
    int p = lane & 15, q = lane >> 4;
    int r0 = rowBase + p, r1 = rowBase + 16 + p;
    int rl0 = r0 < N ? r0 : N - 1;
    int rl1 = r1 < N ? r1 : N - 1;
    int kg = q * 8;

    const short8* ap0 = (const short8*)(agg + (size_t)rl0 * 1024 + part * 512 + kg);
    const short8* ap1 = (const short8*)(agg + (size_t)rl1 * 1024 + part * 512 + kg);
    const u16* wb = Wf + (size_t)part * 65536 + lane * 8;

    f32x4 acc0[8], acc1[8];
    #pragma unroll
    for (int t = 0; t < 8; ++t) {
        acc0[t] = (f32x4){0.f, 0.f, 0.f, 0.f};
        acc1[t] = (f32x4){0.f, 0.f, 0.f, 0.f};
    }

    #pragma unroll
    for (int kk = 0; kk < 16; ++kk) {
        short8 a0 = ap0[kk * 4];
        short8 a1 = ap1[kk * 4];
        #pragma unroll
        for (int t = 0; t < 8; ++t) {
            short8 b = *(const short8*)(wb + (size_t)(t * 16 + kk) * 512);
            acc0[t] = __builtin_amdgcn_mfma_f32_16x16x32_bf16(a0, b, acc0[t], 0, 0, 0);
            acc1[t] = __builtin_amdgcn_mfma_f32_16x16x32_bf16(a1, b, acc1[t], 0, 0, 0);
        }
    }

    #pragma unroll
    for (int t = 0; t < 8; ++t) {
        int col = t * 16 + p;
        float bcol = bias[col];
        #pragma unroll
        for (int j = 0; j < 4; ++j) {
            int rr0 = rowBase + q * 4 + j;
            int rr1 = rowBase + 16 + q * 4 + j;
            if (rr0 < N) {
                float v = acc0[t][j] + bcol;
                if (part == 0) h1b[(size_t)rr0 * C + col] = f2b(v);
                else outf[(size_t)rr0 * C + col] = v;
            }
            if (rr1 < N) {
                float v = acc1[t][j] + bcol;
                if (part == 0) h1b[(size_t)rr1 * C + col] = f2b(v);
                else outf[(size_t)rr1 * C + col] = v;
            }
        }
    }
}

// ---------------- layer-2 post-GEMM: out += A @ W2 + b2 (frag-B, 32 rows/wave) ------

__global__ __launch_bounds__(256) void gemm2c_kernel(const u16* __restrict__ A,
                                                     const u16* __restrict__ Wf,
                                                     const float* __restrict__ bias,
                                                     float* __restrict__ outf, int N) {
    int wave = threadIdx.x >> 6, lane = threadIdx.x & 63;
    int rowBase = blockIdx.x * 128 + wave * 32;
    int p = lane & 15, q = lane >> 4;
    int r0 = rowBase + p, r1 = rowBase + 16 + p;
    int rl0 = r0 < N ? r0 : N - 1;
    int rl1 = r1 < N ? r1 : N - 1;
    int kg = q * 8;

    const short8* ap0 = (const short8*)(A + (size_t)rl0 * 512 + kg);
    const short8* ap1 = (const short8*)(A + (size_t)rl1 * 512 + kg);
    const u16* wb = Wf + (size_t)2 * 65536 + lane * 8;

    f32x4 acc0[8], acc1[8];
    #pragma unroll
    for (int t = 0; t < 8; ++t) {
        acc0[t] = (f32x4){0.f, 0.f, 0.f, 0.f};
        acc1[t] = (f32x4){0.f, 0.f, 0.f, 0.f};
    }

    #pragma unroll
    for (int kk = 0; kk < 16; ++kk) {
        short8 a0 = ap0[kk * 4];
        short8 a1 = ap1[kk * 4];
        #pragma unroll
        for (int t = 0; t < 8; ++t) {
            short8 b = *(const short8*)(wb + (size_t)(t * 16 + kk) * 512);
            acc0[t] = __builtin_amdgcn_mfma_f32_16x16x32_bf16(a0, b, acc0[t], 0, 0, 0);
            acc1[t] = __builtin_amdgcn_mfma_f32_16x16x32_bf16(a1, b, acc1[t], 0, 0, 0);
        }
    }

    #pragma unroll
    for (int t = 0; t < 8; ++t) {
        int col = t * 16 + p;
        float bcol = bias[col];
        #pragma unroll
        for (int j = 0; j < 4; ++j) {
            int rr0 = rowBase + q * 4 + j;
            int rr1 = rowBase + 16 + q * 4 + j;
            if (rr0 < N) outf[(size_t)rr0 * C + col] += acc0[t][j] + bcol;
            if (rr1 < N) outf[(size_t)rr1 * C + col] += acc1[t][j] + bcol;
        }
    }
}

// ---------------- launch ----------------

extern "C" void kernel_launch(void* const* d_in, const int* in_sizes, int n_in,
                              void* d_out, int out_size, void* d_ws, size_t ws_size,
                              hipStream_t stream) {
    const float* x = (const float*)d_in[0];
    const int* ei = (const int*)d_in[1];
    const float* W1 = (const float*)d_in[2];
    const float* as1 = (const float*)d_in[3];
    const float* ad1 = (const float*)d_in[4];
    const float* b1 = (const float*)d_in[5];
    const float* W2 = (const float*)d_in[6];
    const float* as2 = (const float*)d_in[7];
    const float* ad2 = (const float*)d_in[8];
    const float* b2 = (const float*)d_in[9];
    const float* Wr = (const float*)d_in[10];
    const float* asr = (const float*)d_in[11];
    const float* adr = (const float*)d_in[12];
    const float* br = (const float*)d_in[13];

    int N = in_sizes[0] / C;   // 20000
    int E = in_sizes[1] / 2;   // 320000
    int ET = E + N;

    size_t sz_xb    = (size_t)N * C * 2;
    size_t sz_h1b   = (size_t)N * C * 2;
    size_t sz_aggA  = (size_t)N * 1024 * 2;
    size_t sz_aggB  = (size_t)N * 512 * 2;
    size_t sz_wc    = (size_t)3 * C * 512 * 2;
    size_t sz_vsd   = (size_t)16 * C * 2;
    size_t sz_al8   = (size_t)N * 8 * 4;
    size_t sz_count = (size_t)N * 4;
    size_t sz_den8  = (size_t)N * 8 * 4;
    size_t sz_den4  = (size_t)N * 4 * 4;
    size_t sz_offs  = (size_t)(N + 4) * 4;
    size_t sz_srcs  = (size_t)ET * 4;
    size_t sz_w     = (size_t)ET * 8 * 4;
    size_t required = sz_xb + sz_h1b + sz_aggA + sz_aggB + sz_wc + 2 * sz_vsd +
                      2 * sz_al8 + sz_count + sz_den8 + sz_den4 + sz_count +
                      sz_offs + 2 * sz_srcs + sz_w;
    if (ws_size < required) return;

    char* w = (char*)d_ws;
    u16* xb = (u16*)w;        w += sz_xb;
    u16* h1b = (u16*)w;       w += sz_h1b;
    u16* aggA = (u16*)w;      w += sz_aggA;
    u16* aggB = (u16*)w;      w += sz_aggB;
    u16* Wf = (u16*)w;        w += sz_wc;
    u16* vsdA = (u16*)w;      w += sz_vsd;
    u16* vsdB = (u16*)w;      w += sz_vsd;
    float* als = (float*)w;   w += sz_al8;
    float* ald = (float*)w;   w += sz_al8;
    int* count = (int*)w;     w += sz_count;
    float* den8 = (float*)w;  w += sz_den8;
    float* den4 = (float*)w;  w += sz_den4;
    int* cursor = (int*)w;    w += sz_count;
    int* offs = (int*)w;      w += sz_offs;
    int* srcs = (int*)w;      w += sz_srcs;
    int* dsts = (int*)w;      w += sz_srcs;
    float* wgt = (float*)w;   w += sz_w;
    float* out = (float*)d_out;

    hipMemsetAsync(count, 0, sz_count, stream);
    hist_kernel<<<512, 256, 0, stream>>>(ei, E, N, count);
    scan_kernel<<<1, 1024, 0, stream>>>(count, offs, cursor, N);
    scatter_kernel<<<512, 256, 0, stream>>>(ei, E, N, cursor, srcs, dsts);

    cvt_w_kernel<<<96, 256, 0, stream>>>(W1, Wr, W2, Wf);
    wvec_kernel<<<dim3(12, 4), 256, 0, stream>>>(W1, as1, ad1, Wr, asr, adr,
                                                 W2, as2, ad2, vsdA, vsdB);

    int nwb = (N + 3) / 4;
    int neb = (ET + 255) / 256;
    int gx = (N + 63) / 64;
    int gx2 = (N + 127) / 128;
    int nd8 = (N * 8 + 255) / 256;
    int nd4 = (N * 4 + 255) / 256;

    // group A: layer1 + residual (share the x gather)
    alA_kernel<<<gx, 256, 0, stream>>>(x, vsdA, xb, als, ald, N);
    ew_kernel<8><<<neb, 256, 0, stream>>>(als, ald, srcs, dsts, wgt, ET);
    den_kernel<8><<<nd8, 256, 0, stream>>>(wgt, offs, den8, N);
    aggx_kernel<8><<<nwb, 256, 0, stream>>>(xb, wgt, den8, offs, srcs, aggA, N);
    gemm2ab_kernel<<<dim3(gx2, 2), 256, 0, stream>>>(aggA, Wf, b1, br, h1b, out, N);

    // group B: layer2
    alB_kernel<<<gx, 256, 0, stream>>>(h1b, vsdB, als, ald, N);
    ew_kernel<4><<<neb, 256, 0, stream>>>(als, ald, srcs, dsts, wgt, ET);
    den_kernel<4><<<nd4, 256, 0, stream>>>(wgt, offs, den4, N);
    aggx_kernel<4><<<nwb, 256, 0, stream>>>(h1b, wgt, den4, offs, srcs, aggB, N);
    gemm2c_kernel<<<gx2, 256, 0, stream>>>(aggB, Wf, b2, out, N);
}

// Round 13
// 308.976 us; speedup vs baseline: 1.2163x; 1.1843x over previous
//
#include <hip/hip_runtime.h>
#include <math.h>

#define C 128

typedef unsigned short u16;
typedef __attribute__((ext_vector_type(8))) short short8;
typedef __attribute__((ext_vector_type(4))) float f32x4;
typedef __attribute__((ext_vector_type(4))) u16 u16x4;

__device__ __forceinline__ float b2f(u16 u) {
    union { unsigned i; float f; } x; x.i = (unsigned)u << 16; return x.f;
}
__device__ __forceinline__ u16 f2b(float f) {
    union { float f; unsigned i; } x; x.f = f;
    unsigned r = x.i + 0x7FFFu + ((x.i >> 16) & 1u);
    return (u16)(r >> 16);
}
__device__ __forceinline__ float lrelu(float x) { return x > 0.f ? x : 0.2f * x; }

// ---------------- CSR build (edge_index arrives int32) ----------------

__global__ void hist_kernel(const int* __restrict__ ei, int E, int N,
                            int* __restrict__ count) {
    int total = E + N;
    for (int e = blockIdx.x * blockDim.x + threadIdx.x; e < total;
         e += gridDim.x * blockDim.x) {
        int d = (e < E) ? ei[E + e] : (e - E);
        if ((unsigned)d < (unsigned)N) atomicAdd(&count[d], 1);
    }
}

__global__ __launch_bounds__(1024) void scan_kernel(const int* __restrict__ count,
                                                    int* __restrict__ offs,
                                                    int* __restrict__ cursor, int N) {
    int tid = threadIdx.x, lane = tid & 63, wid = tid >> 6;   // 16 waves
    int CH = (N + 1023) >> 10;
    int base = tid * CH;
    int s = 0;
    for (int j = 0; j < CH; ++j) {
        int i = base + j;
        if (i < N) s += count[i];
    }
    int own = s;
    #pragma unroll
    for (int d = 1; d < 64; d <<= 1) {
        int v = __shfl_up(s, d);
        if (lane >= d) s += v;
    }
    __shared__ int wtot[16];
    if (lane == 63) wtot[wid] = s;
    __syncthreads();
    if (tid < 16) {
        int t = wtot[tid];
        int u = t;
        #pragma unroll
        for (int d = 1; d < 16; d <<= 1) {
            int v = __shfl_up(u, d);
            if (tid >= d) u += v;
        }
        wtot[tid] = u - t;            // exclusive wave offset
        if (tid == 15) offs[N] = u;
    }
    __syncthreads();
    int run = wtot[wid] + s - own;
    for (int j = 0; j < CH; ++j) {
        int i = base + j;
        if (i < N) {
            offs[i] = run;
            cursor[i] = run;
            run += count[i];
        }
    }
}

__global__ void scatter_kernel(const int* __restrict__ ei, int E, int N,
                               int* __restrict__ cursor, int* __restrict__ srcs) {
    int total = E + N;
    for (int e = blockIdx.x * blockDim.x + threadIdx.x; e < total;
         e += gridDim.x * blockDim.x) {
        int sNode, d;
        if (e < E) { sNode = ei[e]; d = ei[E + e]; }
        else       { sNode = e - E; d = sNode; }
        if ((unsigned)d < (unsigned)N && (unsigned)sNode < (unsigned)N) {
            int pos = atomicAdd(&cursor[d], 1);
            srcs[pos] = sNode;
        }
    }
}

// ---------------- W -> MFMA-fragment layout (parts: 0=W1, 1=Wr, 2=W2) ------------
// Wf[((l*8 + t)*16 + kk)*512 + lane*8 + j] = 0.25*W_l[h][i][o]
// o = t*16 + (lane&15), khi = kk*32 + (lane>>4)*8 + j, h = khi>>7, i = khi&127.

__global__ __launch_bounds__(256) void cvt_w_kernel(const float* __restrict__ W1,
                                                    const float* __restrict__ Wr,
                                                    const float* __restrict__ W2,
                                                    u16* __restrict__ Wf) {
    int idx = blockIdx.x * 256 + threadIdx.x;   // 24576 groups total
    int lane = idx & 63;
    int kk = (idx >> 6) & 15;
    int t = (idx >> 10) & 7;
    int l = idx >> 13;
    if (l >= 3) return;
    const float* W = (l == 0) ? W1 : (l == 1) ? Wr : W2;
    int o = t * 16 + (lane & 15);
    int bk = kk * 32 + (lane >> 4) * 8;
    int h = bk >> 7, i0 = bk & 127;
    short8 v;
    #pragma unroll
    for (int j = 0; j < 8; ++j) {
        v[j] = (short)f2b(0.25f * W[((size_t)h * C + i0 + j) * C + o]);
    }
    *(short8*)(Wf + (size_t)idx * 8) = v;
}

// ---------------- W@a vectors -> bf16 B-matrices for the al MFMA kernels ----------

__global__ __launch_bounds__(256) void wvec_kernel(const float* __restrict__ W1,
                                                   const float* __restrict__ as1,
                                                   const float* __restrict__ ad1,
                                                   const float* __restrict__ Wr,
                                                   const float* __restrict__ asr,
                                                   const float* __restrict__ adr,
                                                   const float* __restrict__ W2,
                                                   const float* __restrict__ as2,
                                                   const float* __restrict__ ad2,
                                                   u16* __restrict__ vsdA,
                                                   u16* __restrict__ vsdB) {
    int slot = blockIdx.x;        // 0..11
    const float* W  = (slot < 4) ? W1 : (slot < 8) ? Wr : W2;
    const float* s_ = (slot < 4) ? as1 : (slot < 8) ? asr : as2;
    const float* d_ = (slot < 4) ? ad1 : (slot < 8) ? adr : ad2;
    int h = slot & 3;
    int wave = threadIdx.x >> 6, lane = threadIdx.x & 63;
    int rbase = blockIdx.y * 32 + wave * 8;
    float as0 = s_[h * C + lane], as1v = s_[h * C + 64 + lane];
    float ad0 = d_[h * C + lane], ad1v = d_[h * C + 64 + lane];
    #pragma unroll
    for (int j = 0; j < 8; ++j) {
        int i = rbase + j;
        const float* Wrow = W + ((size_t)h * C + i) * C;
        float w0 = Wrow[lane], w1 = Wrow[64 + lane];
        float ps = w0 * as0 + w1 * as1v;
        float pd = w0 * ad0 + w1 * ad1v;
        #pragma unroll
        for (int m = 32; m; m >>= 1) {
            ps += __shfl_xor(ps, m);
            pd += __shfl_xor(pd, m);
        }
        if (lane == 0) {
            if (slot < 8) {
                vsdA[slot * C + i] = f2b(ps);
                vsdA[(8 + slot) * C + i] = f2b(pd);
            } else {
                vsdB[(slot - 8) * C + i] = f2b(ps);
                vsdB[(4 + (slot - 8)) * C + i] = f2b(pd);
            }
        }
    }
}

// ---------------- group-A logits via MFMA, fused with x fp32->bf16 ----------------

__global__ __launch_bounds__(256) void alA_kernel(const float* __restrict__ x,
                                                  const u16* __restrict__ vsd,
                                                  u16* __restrict__ xb,
                                                  float* __restrict__ als,
                                                  float* __restrict__ ald, int N) {
    int wave = threadIdx.x >> 6, lane = threadIdx.x & 63;
    int rowBase = blockIdx.x * 64 + wave * 16;
    int r = rowBase + (lane & 15);
    int rl = r < N ? r : N - 1;
    int kg = (lane >> 4) * 8;

    short8 a[4];
    #pragma unroll
    for (int t = 0; t < 4; ++t) {
        const float* xp = x + (size_t)rl * C + t * 32 + kg;
        float4 f0 = *(const float4*)xp;
        float4 f1 = *(const float4*)(xp + 4);
        short8 s;
        s[0] = f2b(f0.x); s[1] = f2b(f0.y); s[2] = f2b(f0.z); s[3] = f2b(f0.w);
        s[4] = f2b(f1.x); s[5] = f2b(f1.y); s[6] = f2b(f1.z); s[7] = f2b(f1.w);
        a[t] = s;
        if (r < N) *(short8*)(xb + (size_t)r * C + t * 32 + kg) = s;
    }
    f32x4 acc = {0.f, 0.f, 0.f, 0.f};
    int col = lane & 15;
    #pragma unroll
    for (int t = 0; t < 4; ++t) {
        short8 b = *(const short8*)(vsd + (size_t)col * C + t * 32 + kg);
        acc = __builtin_amdgcn_mfma_f32_16x16x32_bf16(a[t], b, acc, 0, 0, 0);
    }
    #pragma unroll
    for (int j = 0; j < 4; ++j) {
        int rr = rowBase + (lane >> 4) * 4 + j;
        if (rr < N) {
            if (col < 8) als[rr * 8 + col] = acc[j];
            else ald[rr * 8 + (col - 8)] = acc[j];
        }
    }
}

// ---------------- group-B logits via MFMA (h1b bf16 input) ----------------

__global__ __launch_bounds__(256) void alB_kernel(const u16* __restrict__ in,
                                                  const u16* __restrict__ vsd,
                                                  float* __restrict__ als,
                                                  float* __restrict__ ald, int N) {
    int wave = threadIdx.x >> 6, lane = threadIdx.x & 63;
    int rowBase = blockIdx.x * 64 + wave * 16;
    int r = rowBase + (lane & 15);
    int rl = r < N ? r : N - 1;
    int kg = (lane >> 4) * 8;

    f32x4 acc = {0.f, 0.f, 0.f, 0.f};
    int col = lane & 15;
    #pragma unroll
    for (int t = 0; t < 4; ++t) {
        short8 a = *(const short8*)(in + (size_t)rl * C + t * 32 + kg);
        short8 b = *(const short8*)(vsd + (size_t)col * C + t * 32 + kg);
        acc = __builtin_amdgcn_mfma_f32_16x16x32_bf16(a, b, acc, 0, 0, 0);
    }
    #pragma unroll
    for (int j = 0; j < 4; ++j) {
        int rr = rowBase + (lane >> 4) * 4 + j;
        if (rr < N && col < 8) {
            if (col < 4) als[rr * 4 + col] = acc[j];
            else ald[rr * 4 + (col - 4)] = acc[j];
        }
    }
}

// ---------------- fused weights + denominators (node,head)-parallel --------------

template <int NH>
__global__ __launch_bounds__(256) void denf_kernel(const float* __restrict__ als,
                                                   const float* __restrict__ ald,
                                                   const int* __restrict__ offs,
                                                   const int* __restrict__ srcs,
                                                   float* __restrict__ wgt,
                                                   float* __restrict__ den, int N) {
    int idx = blockIdx.x * blockDim.x + threadIdx.x;
    int node = idx / NH, h = idx % NH;
    if (node >= N) return;
    float adh = ald[(size_t)node * NH + h];
    int beg = offs[node], end = offs[node + 1];
    float s = 0.f;
    for (int i = beg; i < end; ++i) {
        float w = __expf(lrelu(als[(size_t)srcs[i] * NH + h] + adh));
        wgt[(size_t)i * NH + h] = w;
        s += w;
    }
    den[idx] = s;
}

// ---------------- aggregation: dest[n][h*128+c] = (1/den[n,h]) * sum w[e,h]*xsrc[c] --

template <int NH>
__global__ __launch_bounds__(256) void aggx_kernel(const u16* __restrict__ xsrc,
                                                   const float* __restrict__ wgt,
                                                   const float* __restrict__ den,
                                                   const int* __restrict__ offs,
                                                   const int* __restrict__ srcs,
                                                   u16* __restrict__ dest, int N) {
    constexpr int NHG = NH / 2;
    int node = blockIdx.x * 4 + (threadIdx.x >> 6);
    int lane = threadIdx.x & 63;
    if (node >= N) return;
    int g = lane >> 5;
    int c0 = (lane & 31) * 4;
    int beg = offs[node], end = offs[node + 1];

    float inv[NHG];
    #pragma unroll
    for (int j = 0; j < NHG; ++j) {
        inv[j] = 1.f / den[(size_t)node * NH + g * NHG + j];
    }

    float acc[NHG][4] = {};
    int i = beg;
    for (; i + 8 <= end; i += 8) {
        int s[8];
        #pragma unroll
        for (int e = 0; e < 8; ++e) s[e] = srcs[i + e];
        u16x4 v[8];
        #pragma unroll
        for (int e = 0; e < 8; ++e) {
            v[e] = *(const u16x4*)(xsrc + (size_t)s[e] * C + c0);
        }
        float wv[8][NHG];
        #pragma unroll
        for (int e = 0; e < 8; ++e) {
            if constexpr (NHG == 4) {
                float4 wq = *(const float4*)(wgt + (size_t)(i + e) * NH + g * NHG);
                wv[e][0] = wq.x; wv[e][1] = wq.y; wv[e][2] = wq.z; wv[e][3] = wq.w;
            } else {
                float2 wq = *(const float2*)(wgt + (size_t)(i + e) * NH + g * NHG);
                wv[e][0] = wq.x; wv[e][1] = wq.y;
            }
        }
        #pragma unroll
        for (int e = 0; e < 8; ++e) {
            float f[4];
            #pragma unroll
            for (int j = 0; j < 4; ++j) f[j] = b2f(v[e][j]);
            #pragma unroll
            for (int j2 = 0; j2 < NHG; ++j2) {
                #pragma unroll
                for (int j = 0; j < 4; ++j) acc[j2][j] += wv[e][j2] * f[j];
            }
        }
    }
    for (; i < end; ++i) {
        int s0 = srcs[i];
        u16x4 v0 = *(const u16x4*)(xsrc + (size_t)s0 * C + c0);
        float w0[NHG];
        #pragma unroll
        for (int j2 = 0; j2 < NHG; ++j2) {
            w0[j2] = wgt[(size_t)i * NH + g * NHG + j2];
        }
        float f[4];
        #pragma unroll
        for (int j = 0; j < 4; ++j) f[j] = b2f(v0[j]);
        #pragma unroll
        for (int j2 = 0; j2 < NHG; ++j2) {
            #pragma unroll
            for (int j = 0; j < 4; ++j) acc[j2][j] += w0[j2] * f[j];
        }
    }

    #pragma unroll
    for (int j2 = 0; j2 < NHG; ++j2) {
        int h = g * NHG + j2;
        u16x4 o = {f2b(acc[j2][0] * inv[j2]), f2b(acc[j2][1] * inv[j2]),
                   f2b(acc[j2][2] * inv[j2]), f2b(acc[j2][3] * inv[j2])};
        *(u16x4*)(dest + (size_t)node * (NH * C) + h * C + c0) = o;
    }
}

// ---------------- layer-1 GEMM: h1b = aggA[:, 0:512] @ W1 + b1 (bf16 out) ----------
// 16 rows/wave, 64 cols/wave (col-half = blockIdx.y). grid (ceil(N/64), 2).

__global__ __launch_bounds__(256) void gemmL1_kernel(const u16* __restrict__ agg,
                                                     const u16* __restrict__ Wf,
                                                     const float* __restrict__ b1,
                                                     u16* __restrict__ h1b, int N) {
    int wave = threadIdx.x >> 6, lane = threadIdx.x & 63;
    int ch = blockIdx.y;
    int rowBase = blockIdx.x * 64 + wave * 16;
    int p = lane & 15, q = lane >> 4;
    int r = rowBase + p;
    int rl = r < N ? r : N - 1;
    int kg = q * 8;

    const short8* ap = (const short8*)(agg + (size_t)rl * 1024 + kg);
    const u16* wb = Wf + (size_t)(ch * 4 * 16) * 512 + lane * 8;

    f32x4 acc[4];
    #pragma unroll
    for (int t = 0; t < 4; ++t) acc[t] = (f32x4){0.f, 0.f, 0.f, 0.f};

    #pragma unroll
    for (int kk = 0; kk < 16; ++kk) {
        short8 a = ap[kk * 4];
        #pragma unroll
        for (int t = 0; t < 4; ++t) {
            short8 b = *(const short8*)(wb + (size_t)(t * 16 + kk) * 512);
            acc[t] = __builtin_amdgcn_mfma_f32_16x16x32_bf16(a, b, acc[t], 0, 0, 0);
        }
    }

    #pragma unroll
    for (int t = 0; t < 4; ++t) {
        int col = (ch * 4 + t) * 16 + p;
        float bcol = b1[col];
        #pragma unroll
        for (int j = 0; j < 4; ++j) {
            int rr = rowBase + q * 4 + j;
            if (rr < N) h1b[(size_t)rr * C + col] = f2b(acc[t][j] + bcol);
        }
    }
}

// ---------------- final GEMM: out = aggB@W2 + aggA[:,512:]@Wr + b2 + br ------------
// Single f32 write; two K=512 segments into one accumulator.

__global__ __launch_bounds__(256) void gemmF_kernel(const u16* __restrict__ aggB,
                                                    const u16* __restrict__ aggA,
                                                    const u16* __restrict__ Wf,
                                                    const float* __restrict__ b2,
                                                    const float* __restrict__ br,
                                                    float* __restrict__ outf, int N) {
    int wave = threadIdx.x >> 6, lane = threadIdx.x & 63;
    int ch = blockIdx.y;
    int rowBase = blockIdx.x * 64 + wave * 16;
    int p = lane & 15, q = lane >> 4;
    int r = rowBase + p;
    int rl = r < N ? r : N - 1;
    int kg = q * 8;

    const short8* apB = (const short8*)(aggB + (size_t)rl * 512 + kg);
    const short8* apR = (const short8*)(aggA + (size_t)rl * 1024 + 512 + kg);
    const u16* wb2 = Wf + (size_t)2 * 65536 + (size_t)(ch * 4 * 16) * 512 + lane * 8;
    const u16* wbr = Wf + (size_t)1 * 65536 + (size_t)(ch * 4 * 16) * 512 + lane * 8;

    f32x4 acc[4];
    #pragma unroll
    for (int t = 0; t < 4; ++t) acc[t] = (f32x4){0.f, 0.f, 0.f, 0.f};

    #pragma unroll
    for (int kk = 0; kk < 16; ++kk) {
        short8 a = apB[kk * 4];
        #pragma unroll
        for (int t = 0; t < 4; ++t) {
            short8 b = *(const short8*)(wb2 + (size_t)(t * 16 + kk) * 512);
            acc[t] = __builtin_amdgcn_mfma_f32_16x16x32_bf16(a, b, acc[t], 0, 0, 0);
        }
    }
    #pragma unroll
    for (int kk = 0; kk < 16; ++kk) {
        short8 a = apR[kk * 4];
        #pragma unroll
        for (int t = 0; t < 4; ++t) {
            short8 b = *(const short8*)(wbr + (size_t)(t * 16 + kk) * 512);
            acc[t] = __builtin_amdgcn_mfma_f32_16x16x32_bf16(a, b, acc[t], 0, 0, 0);
        }
    }

    #pragma unroll
    for (int t = 0; t < 4; ++t) {
        int col = (ch * 4 + t) * 16 + p;
        float bcol = b2[col] + br[col];
        #pragma unroll
        for (int j = 0; j < 4; ++j) {
            int rr = rowBase + q * 4 + j;
            if (rr < N) outf[(size_t)rr * C + col] = acc[t][j] + bcol;
        }
    }
}

// ---------------- launch ----------------

extern "C" void kernel_launch(void* const* d_in, const int* in_sizes, int n_in,
                              void* d_out, int out_size, void* d_ws, size_t ws_size,
                              hipStream_t stream) {
    const float* x = (const float*)d_in[0];
    const int* ei = (const int*)d_in[1];
    const float* W1 = (const float*)d_in[2];
    const float* as1 = (const float*)d_in[3];
    const float* ad1 = (const float*)d_in[4];
    const float* b1 = (const float*)d_in[5];
    const float* W2 = (const float*)d_in[6];
    const float* as2 = (const float*)d_in[7];
    const float* ad2 = (const float*)d_in[8];
    const float* b2 = (const float*)d_in[9];
    const float* Wr = (const float*)d_in[10];
    const float* asr = (const float*)d_in[11];
    const float* adr = (const float*)d_in[12];
    const float* br = (const float*)d_in[13];

    int N = in_sizes[0] / C;   // 20000
    int E = in_sizes[1] / 2;   // 320000
    int ET = E + N;

    size_t sz_xb    = (size_t)N * C * 2;
    size_t sz_h1b   = (size_t)N * C * 2;
    size_t sz_aggA  = (size_t)N * 1024 * 2;   // halves: [0:512]=layer1, [512:1024]=resid
    size_t sz_aggB  = (size_t)N * 512 * 2;
    size_t sz_wc    = (size_t)3 * C * 512 * 2;
    size_t sz_vsd   = (size_t)16 * C * 2;
    size_t sz_al8   = (size_t)N * 8 * 4;
    size_t sz_count = (size_t)N * 4;
    size_t sz_den8  = (size_t)N * 8 * 4;
    size_t sz_den4  = (size_t)N * 4 * 4;
    size_t sz_offs  = (size_t)(N + 4) * 4;
    size_t sz_srcs  = (size_t)ET * 4;
    size_t sz_w     = (size_t)ET * 8 * 4;
    size_t required = sz_xb + sz_h1b + sz_aggA + sz_aggB + sz_wc + 2 * sz_vsd +
                      2 * sz_al8 + sz_count + sz_den8 + sz_den4 + sz_count +
                      sz_offs + 2 * sz_srcs + sz_w;
    if (ws_size < required) return;

    char* w = (char*)d_ws;
    u16* xb = (u16*)w;        w += sz_xb;
    u16* h1b = (u16*)w;       w += sz_h1b;
    u16* aggA = (u16*)w;      w += sz_aggA;
    u16* aggB = (u16*)w;      w += sz_aggB;
    u16* Wf = (u16*)w;        w += sz_wc;
    u16* vsdA = (u16*)w;      w += sz_vsd;
    u16* vsdB = (u16*)w;      w += sz_vsd;
    float* als = (float*)w;   w += sz_al8;
    float* ald = (float*)w;   w += sz_al8;
    int* count = (int*)w;     w += sz_count;
    float* den8 = (float*)w;  w += sz_den8;
    float* den4 = (float*)w;  w += sz_den4;
    int* cursor = (int*)w;    w += sz_count;
    int* offs = (int*)w;      w += sz_offs;
    int* srcs = (int*)w;      w += sz_srcs;
    w += sz_srcs;             // (reserved)
    float* wgt = (float*)w;   w += sz_w;
    float* out = (float*)d_out;

    hipMemsetAsync(count, 0, sz_count, stream);
    hist_kernel<<<512, 256, 0, stream>>>(ei, E, N, count);
    scan_kernel<<<1, 1024, 0, stream>>>(count, offs, cursor, N);
    scatter_kernel<<<512, 256, 0, stream>>>(ei, E, N, cursor, srcs);

    cvt_w_kernel<<<96, 256, 0, stream>>>(W1, Wr, W2, Wf);
    wvec_kernel<<<dim3(12, 4), 256, 0, stream>>>(W1, as1, ad1, Wr, asr, adr,
                                                 W2, as2, ad2, vsdA, vsdB);

    int nwb = (N + 3) / 4;
    int gx = (N + 63) / 64;
    int nd8 = (N * 8 + 255) / 256;
    int nd4 = (N * 4 + 255) / 256;

    // group A: layer1 + residual (share the x gather)
    alA_kernel<<<gx, 256, 0, stream>>>(x, vsdA, xb, als, ald, N);
    denf_kernel<8><<<nd8, 256, 0, stream>>>(als, ald, offs, srcs, wgt, den8, N);
    aggx_kernel<8><<<nwb, 256, 0, stream>>>(xb, wgt, den8, offs, srcs, aggA, N);
    gemmL1_kernel<<<dim3(gx, 2), 256, 0, stream>>>(aggA, Wf, b1, h1b, N);

    // group B: layer2 (+ fused residual GEMM at the end)
    alB_kernel<<<gx, 256, 0, stream>>>(h1b, vsdB, als, ald, N);
    denf_kernel<4><<<nd4, 256, 0, stream>>>(als, ald, offs, srcs, wgt, den4, N);
    aggx_kernel<4><<<nwb, 256, 0, stream>>>(h1b, wgt, den4, offs, srcs, aggB, N);
    gemmF_kernel<<<dim3(gx, 2), 256, 0, stream>>>(aggB, aggA, Wf, b2, br, out, N);
}

// Round 14
// 307.788 us; speedup vs baseline: 1.2210x; 1.0039x over previous
//
#include <hip/hip_runtime.h>
#include <math.h>

#define C 128

typedef unsigned short u16;
typedef __attribute__((ext_vector_type(8))) short short8;
typedef __attribute__((ext_vector_type(4))) float f32x4;
typedef __attribute__((ext_vector_type(4))) u16 u16x4;

__device__ __forceinline__ float b2f(u16 u) {
    union { unsigned i; float f; } x; x.i = (unsigned)u << 16; return x.f;
}
__device__ __forceinline__ u16 f2b(float f) {
    union { float f; unsigned i; } x; x.f = f;
    unsigned r = x.i + 0x7FFFu + ((x.i >> 16) & 1u);
    return (u16)(r >> 16);
}
__device__ __forceinline__ float lrelu(float x) { return x > 0.f ? x : 0.2f * x; }

// ---------------- CSR build (edge_index arrives int32) ----------------

__global__ void hist_kernel(const int* __restrict__ ei, int E, int N,
                            int* __restrict__ count) {
    int total = E + N;
    for (int e = blockIdx.x * blockDim.x + threadIdx.x; e < total;
         e += gridDim.x * blockDim.x) {
        int d = (e < E) ? ei[E + e] : (e - E);
        if ((unsigned)d < (unsigned)N) atomicAdd(&count[d], 1);
    }
}

__global__ __launch_bounds__(1024) void scan_kernel(const int* __restrict__ count,
                                                    int* __restrict__ offs,
                                                    int* __restrict__ cursor, int N) {
    int tid = threadIdx.x, lane = tid & 63, wid = tid >> 6;   // 16 waves
    int CH = (N + 1023) >> 10;
    int base = tid * CH;
    int s = 0;
    for (int j = 0; j < CH; ++j) {
        int i = base + j;
        if (i < N) s += count[i];
    }
    int own = s;
    #pragma unroll
    for (int d = 1; d < 64; d <<= 1) {
        int v = __shfl_up(s, d);
        if (lane >= d) s += v;
    }
    __shared__ int wtot[16];
    if (lane == 63) wtot[wid] = s;
    __syncthreads();
    if (tid < 16) {
        int t = wtot[tid];
        int u = t;
        #pragma unroll
        for (int d = 1; d < 16; d <<= 1) {
            int v = __shfl_up(u, d);
            if (tid >= d) u += v;
        }
        wtot[tid] = u - t;            // exclusive wave offset
        if (tid == 15) offs[N] = u;
    }
    __syncthreads();
    int run = wtot[wid] + s - own;
    for (int j = 0; j < CH; ++j) {
        int i = base + j;
        if (i < N) {
            offs[i] = run;
            cursor[i] = run;
            run += count[i];
        }
    }
}

__global__ void scatter_kernel(const int* __restrict__ ei, int E, int N,
                               int* __restrict__ cursor, int* __restrict__ srcs,
                               int* __restrict__ dsts) {
    int total = E + N;
    for (int e = blockIdx.x * blockDim.x + threadIdx.x; e < total;
         e += gridDim.x * blockDim.x) {
        int sNode, d;
        if (e < E) { sNode = ei[e]; d = ei[E + e]; }
        else       { sNode = e - E; d = sNode; }
        if ((unsigned)d < (unsigned)N && (unsigned)sNode < (unsigned)N) {
            int pos = atomicAdd(&cursor[d], 1);
            srcs[pos] = sNode;
            dsts[pos] = d;
        }
    }
}

// ---------------- W -> MFMA-fragment layout (parts: 0=W1, 1=Wr, 2=W2) ------------

__global__ __launch_bounds__(256) void cvt_w_kernel(const float* __restrict__ W1,
                                                    const float* __restrict__ Wr,
                                                    const float* __restrict__ W2,
                                                    u16* __restrict__ Wf) {
    int idx = blockIdx.x * 256 + threadIdx.x;   // 24576 groups total
    int lane = idx & 63;
    int kk = (idx >> 6) & 15;
    int t = (idx >> 10) & 7;
    int l = idx >> 13;
    if (l >= 3) return;
    const float* W = (l == 0) ? W1 : (l == 1) ? Wr : W2;
    int o = t * 16 + (lane & 15);
    int bk = kk * 32 + (lane >> 4) * 8;
    int h = bk >> 7, i0 = bk & 127;
    short8 v;
    #pragma unroll
    for (int j = 0; j < 8; ++j) {
        v[j] = (short)f2b(0.25f * W[((size_t)h * C + i0 + j) * C + o]);
    }
    *(short8*)(Wf + (size_t)idx * 8) = v;
}

// ---------------- W@a vectors -> bf16 B-matrices for the al MFMA kernels ----------

__global__ __launch_bounds__(256) void wvec_kernel(const float* __restrict__ W1,
                                                   const float* __restrict__ as1,
                                                   const float* __restrict__ ad1,
                                                   const float* __restrict__ Wr,
                                                   const float* __restrict__ asr,
                                                   const float* __restrict__ adr,
                                                   const float* __restrict__ W2,
                                                   const float* __restrict__ as2,
                                                   const float* __restrict__ ad2,
                                                   u16* __restrict__ vsdA,
                                                   u16* __restrict__ vsdB) {
    int slot = blockIdx.x;        // 0..11
    const float* W  = (slot < 4) ? W1 : (slot < 8) ? Wr : W2;
    const float* s_ = (slot < 4) ? as1 : (slot < 8) ? asr : as2;
    const float* d_ = (slot < 4) ? ad1 : (slot < 8) ? adr : ad2;
    int h = slot & 3;
    int wave = threadIdx.x >> 6, lane = threadIdx.x & 63;
    int rbase = blockIdx.y * 32 + wave * 8;
    float as0 = s_[h * C + lane], as1v = s_[h * C + 64 + lane];
    float ad0 = d_[h * C + lane], ad1v = d_[h * C + 64 + lane];
    #pragma unroll
    for (int j = 0; j < 8; ++j) {
        int i = rbase + j;
        const float* Wrow = W + ((size_t)h * C + i) * C;
        float w0 = Wrow[lane], w1 = Wrow[64 + lane];
        float ps = w0 * as0 + w1 * as1v;
        float pd = w0 * ad0 + w1 * ad1v;
        #pragma unroll
        for (int m = 32; m; m >>= 1) {
            ps += __shfl_xor(ps, m);
            pd += __shfl_xor(pd, m);
        }
        if (lane == 0) {
            if (slot < 8) {
                vsdA[slot * C + i] = f2b(ps);
                vsdA[(8 + slot) * C + i] = f2b(pd);
            } else {
                vsdB[(slot - 8) * C + i] = f2b(ps);
                vsdB[(4 + (slot - 8)) * C + i] = f2b(pd);
            }
        }
    }
}

// ---------------- group-A logits via MFMA, fused with x fp32->bf16 ----------------

__global__ __launch_bounds__(256) void alA_kernel(const float* __restrict__ x,
                                                  const u16* __restrict__ vsd,
                                                  u16* __restrict__ xb,
                                                  float* __restrict__ als,
                                                  float* __restrict__ ald, int N) {
    int wave = threadIdx.x >> 6, lane = threadIdx.x & 63;
    int rowBase = blockIdx.x * 64 + wave * 16;
    int r = rowBase + (lane & 15);
    int rl = r < N ? r : N - 1;
    int kg = (lane >> 4) * 8;

    short8 a[4];
    #pragma unroll
    for (int t = 0; t < 4; ++t) {
        const float* xp = x + (size_t)rl * C + t * 32 + kg;
        float4 f0 = *(const float4*)xp;
        float4 f1 = *(const float4*)(xp + 4);
        short8 s;
        s[0] = f2b(f0.x); s[1] = f2b(f0.y); s[2] = f2b(f0.z); s[3] = f2b(f0.w);
        s[4] = f2b(f1.x); s[5] = f2b(f1.y); s[6] = f2b(f1.z); s[7] = f2b(f1.w);
        a[t] = s;
        if (r < N) *(short8*)(xb + (size_t)r * C + t * 32 + kg) = s;
    }
    f32x4 acc = {0.f, 0.f, 0.f, 0.f};
    int col = lane & 15;
    #pragma unroll
    for (int t = 0; t < 4; ++t) {
        short8 b = *(const short8*)(vsd + (size_t)col * C + t * 32 + kg);
        acc = __builtin_amdgcn_mfma_f32_16x16x32_bf16(a[t], b, acc, 0, 0, 0);
    }
    #pragma unroll
    for (int j = 0; j < 4; ++j) {
        int rr = rowBase + (lane >> 4) * 4 + j;
        if (rr < N) {
            if (col < 8) als[rr * 8 + col] = acc[j];
            else ald[rr * 8 + (col - 8)] = acc[j];
        }
    }
}

// ---------------- group-B logits via MFMA (h1b bf16 input) ----------------

__global__ __launch_bounds__(256) void alB_kernel(const u16* __restrict__ in,
                                                  const u16* __restrict__ vsd,
                                                  float* __restrict__ als,
                                                  float* __restrict__ ald, int N) {
    int wave = threadIdx.x >> 6, lane = threadIdx.x & 63;
    int rowBase = blockIdx.x * 64 + wave * 16;
    int r = rowBase + (lane & 15);
    int rl = r < N ? r : N - 1;
    int kg = (lane >> 4) * 8;

    f32x4 acc = {0.f, 0.f, 0.f, 0.f};
    int col = lane & 15;
    #pragma unroll
    for (int t = 0; t < 4; ++t) {
        short8 a = *(const short8*)(in + (size_t)rl * C + t * 32 + kg);
        short8 b = *(const short8*)(vsd + (size_t)col * C + t * 32 + kg);
        acc = __builtin_amdgcn_mfma_f32_16x16x32_bf16(a, b, acc, 0, 0, 0);
    }
    #pragma unroll
    for (int j = 0; j < 4; ++j) {
        int rr = rowBase + (lane >> 4) * 4 + j;
        if (rr < N && col < 8) {
            if (col < 4) als[rr * 4 + col] = acc[j];
            else ald[rr * 4 + (col - 4)] = acc[j];
        }
    }
}

// ---------------- edge-parallel unnormalized weights (no atomics) ----------------

template <int NH>
__global__ __launch_bounds__(256) void ew_kernel(const float* __restrict__ als,
                                                 const float* __restrict__ ald,
                                                 const int* __restrict__ srcs,
                                                 const int* __restrict__ dsts,
                                                 float* __restrict__ wout, int ET) {
    int i = blockIdx.x * blockDim.x + threadIdx.x;
    if (i >= ET) return;
    int s = srcs[i], d = dsts[i];
    const float* as_ = als + (size_t)s * NH;
    const float* ad_ = ald + (size_t)d * NH;
    float* wo = wout + (size_t)i * NH;
    #pragma unroll
    for (int h = 0; h < NH; ++h) {
        wo[h] = __expf(lrelu(as_[h] + ad_[h]));
    }
}

// ---------------- aggregation with srcs-prefetch + in-register denominators -------
// dest[n][h*128+c] = (sum_e w[e,h]*xsrc[c]) / (sum_e w[e,h])

template <int NH>
__global__ __launch_bounds__(256) void aggx_kernel(const u16* __restrict__ xsrc,
                                                   const float* __restrict__ wgt,
                                                   const int* __restrict__ offs,
                                                   const int* __restrict__ srcs,
                                                   u16* __restrict__ dest, int N) {
    constexpr int NHG = NH / 2;
    int node = blockIdx.x * 4 + (threadIdx.x >> 6);
    int lane = threadIdx.x & 63;
    if (node >= N) return;
    int g = lane >> 5;
    int c0 = (lane & 31) * 4;
    int beg = offs[node], end = offs[node + 1];

    float dacc[NHG] = {};
    float acc[NHG][4] = {};

    int i = beg;
    int iend8 = beg + ((end - beg) & ~7);

    if (i < iend8) {
        int sA[8];
        #pragma unroll
        for (int e = 0; e < 8; ++e) sA[e] = srcs[i + e];
        while (i < iend8) {
            int inext = i + 8;
            // prefetch next batch's indices (addresses are in-bounds of ws even
            // past the node's segment; values only used if the loop continues)
            int sB[8];
            #pragma unroll
            for (int e = 0; e < 8; ++e) sB[e] = srcs[inext + e];

            u16x4 v[8];
            #pragma unroll
            for (int e = 0; e < 8; ++e) {
                v[e] = *(const u16x4*)(xsrc + (size_t)sA[e] * C + c0);
            }
            float wv[8][NHG];
            #pragma unroll
            for (int e = 0; e < 8; ++e) {
                if constexpr (NHG == 4) {
                    float4 wq = *(const float4*)(wgt + (size_t)(i + e) * NH + g * NHG);
                    wv[e][0] = wq.x; wv[e][1] = wq.y; wv[e][2] = wq.z; wv[e][3] = wq.w;
                } else {
                    float2 wq = *(const float2*)(wgt + (size_t)(i + e) * NH + g * NHG);
                    wv[e][0] = wq.x; wv[e][1] = wq.y;
                }
            }
            #pragma unroll
            for (int e = 0; e < 8; ++e) {
                float f[4];
                #pragma unroll
                for (int j = 0; j < 4; ++j) f[j] = b2f(v[e][j]);
                #pragma unroll
                for (int j2 = 0; j2 < NHG; ++j2) {
                    dacc[j2] += wv[e][j2];
                    #pragma unroll
                    for (int j = 0; j < 4; ++j) acc[j2][j] += wv[e][j2] * f[j];
                }
            }
            #pragma unroll
            for (int e = 0; e < 8; ++e) sA[e] = sB[e];
            i = inext;
        }
    }
    for (; i < end; ++i) {
        int s0 = srcs[i];
        u16x4 v0 = *(const u16x4*)(xsrc + (size_t)s0 * C + c0);
        float w0[NHG];
        #pragma unroll
        for (int j2 = 0; j2 < NHG; ++j2) {
            w0[j2] = wgt[(size_t)i * NH + g * NHG + j2];
        }
        float f[4];
        #pragma unroll
        for (int j = 0; j < 4; ++j) f[j] = b2f(v0[j]);
        #pragma unroll
        for (int j2 = 0; j2 < NHG; ++j2) {
            dacc[j2] += w0[j2];
            #pragma unroll
            for (int j = 0; j < 4; ++j) acc[j2][j] += w0[j2] * f[j];
        }
    }

    #pragma unroll
    for (int j2 = 0; j2 < NHG; ++j2) {
        float inv = 1.f / dacc[j2];
        int h = g * NHG + j2;
        u16x4 o = {f2b(acc[j2][0] * inv), f2b(acc[j2][1] * inv),
                   f2b(acc[j2][2] * inv), f2b(acc[j2][3] * inv)};
        *(u16x4*)(dest + (size_t)node * (NH * C) + h * C + c0) = o;
    }
}

// ---------------- layer-1 GEMM: h1b = aggA[:, 0:512] @ W1 + b1 (bf16 out) ----------

__global__ __launch_bounds__(256) void gemmL1_kernel(const u16* __restrict__ agg,
                                                     const u16* __restrict__ Wf,
                                                     const float* __restrict__ b1,
                                                     u16* __restrict__ h1b, int N) {
    int wave = threadIdx.x >> 6, lane = threadIdx.x & 63;
    int ch = blockIdx.y;
    int rowBase = blockIdx.x * 64 + wave * 16;
    int p = lane & 15, q = lane >> 4;
    int r = rowBase + p;
    int rl = r < N ? r : N - 1;
    int kg = q * 8;

    const short8* ap = (const short8*)(agg + (size_t)rl * 1024 + kg);
    const u16* wb = Wf + (size_t)(ch * 4 * 16) * 512 + lane * 8;

    f32x4 acc[4];
    #pragma unroll
    for (int t = 0; t < 4; ++t) acc[t] = (f32x4){0.f, 0.f, 0.f, 0.f};

    #pragma unroll
    for (int kk = 0; kk < 16; ++kk) {
        short8 a = ap[kk * 4];
        #pragma unroll
        for (int t = 0; t < 4; ++t) {
            short8 b = *(const short8*)(wb + (size_t)(t * 16 + kk) * 512);
            acc[t] = __builtin_amdgcn_mfma_f32_16x16x32_bf16(a, b, acc[t], 0, 0, 0);
        }
    }

    #pragma unroll
    for (int t = 0; t < 4; ++t) {
        int col = (ch * 4 + t) * 16 + p;
        float bcol = b1[col];
        #pragma unroll
        for (int j = 0; j < 4; ++j) {
            int rr = rowBase + q * 4 + j;
            if (rr < N) h1b[(size_t)rr * C + col] = f2b(acc[t][j] + bcol);
        }
    }
}

// ---------------- final GEMM: out = aggB@W2 + aggA[:,512:]@Wr + b2 + br ------------

__global__ __launch_bounds__(256) void gemmF_kernel(const u16* __restrict__ aggB,
                                                    const u16* __restrict__ aggA,
                                                    const u16* __restrict__ Wf,
                                                    const float* __restrict__ b2,
                                                    const float* __restrict__ br,
                                                    float* __restrict__ outf, int N) {
    int wave = threadIdx.x >> 6, lane = threadIdx.x & 63;
    int ch = blockIdx.y;
    int rowBase = blockIdx.x * 64 + wave * 16;
    int p = lane & 15, q = lane >> 4;
    int r = rowBase + p;
    int rl = r < N ? r : N - 1;
    int kg = q * 8;

    const short8* apB = (const short8*)(aggB + (size_t)rl * 512 + kg);
    const short8* apR = (const short8*)(aggA + (size_t)rl * 1024 + 512 + kg);
    const u16* wb2 = Wf + (size_t)2 * 65536 + (size_t)(ch * 4 * 16) * 512 + lane * 8;
    const u16* wbr = Wf + (size_t)1 * 65536 + (size_t)(ch * 4 * 16) * 512 + lane * 8;

    f32x4 acc[4];
    #pragma unroll
    for (int t = 0; t < 4; ++t) acc[t] = (f32x4){0.f, 0.f, 0.f, 0.f};

    #pragma unroll
    for (int kk = 0; kk < 16; ++kk) {
        short8 a = apB[kk * 4];
        #pragma unroll
        for (int t = 0; t < 4; ++t) {
            short8 b = *(const short8*)(wb2 + (size_t)(t * 16 + kk) * 512);
            acc[t] = __builtin_amdgcn_mfma_f32_16x16x32_bf16(a, b, acc[t], 0, 0, 0);
        }
    }
    #pragma unroll
    for (int kk = 0; kk < 16; ++kk) {
        short8 a = apR[kk * 4];
        #pragma unroll
        for (int t = 0; t < 4; ++t) {
            short8 b = *(const short8*)(wbr + (size_t)(t * 16 + kk) * 512);
            acc[t] = __builtin_amdgcn_mfma_f32_16x16x32_bf16(a, b, acc[t], 0, 0, 0);
        }
    }

    #pragma unroll
    for (int t = 0; t < 4; ++t) {
        int col = (ch * 4 + t) * 16 + p;
        float bcol = b2[col] + br[col];
        #pragma unroll
        for (int j = 0; j < 4; ++j) {
            int rr = rowBase + q * 4 + j;
            if (rr < N) outf[(size_t)rr * C + col] = acc[t][j] + bcol;
        }
    }
}

// ---------------- launch ----------------

extern "C" void kernel_launch(void* const* d_in, const int* in_sizes, int n_in,
                              void* d_out, int out_size, void* d_ws, size_t ws_size,
                              hipStream_t stream) {
    const float* x = (const float*)d_in[0];
    const int* ei = (const int*)d_in[1];
    const float* W1 = (const float*)d_in[2];
    const float* as1 = (const float*)d_in[3];
    const float* ad1 = (const float*)d_in[4];
    const float* b1 = (const float*)d_in[5];
    const float* W2 = (const float*)d_in[6];
    const float* as2 = (const float*)d_in[7];
    const float* ad2 = (const float*)d_in[8];
    const float* b2 = (const float*)d_in[9];
    const float* Wr = (const float*)d_in[10];
    const float* asr = (const float*)d_in[11];
    const float* adr = (const float*)d_in[12];
    const float* br = (const float*)d_in[13];

    int N = in_sizes[0] / C;   // 20000
    int E = in_sizes[1] / 2;   // 320000
    int ET = E + N;

    size_t sz_xb    = (size_t)N * C * 2;
    size_t sz_h1b   = (size_t)N * C * 2;
    size_t sz_aggA  = (size_t)N * 1024 * 2;   // halves: [0:512]=layer1, [512:1024]=resid
    size_t sz_aggB  = (size_t)N * 512 * 2;
    size_t sz_wc    = (size_t)3 * C * 512 * 2;
    size_t sz_vsd   = (size_t)16 * C * 2;
    size_t sz_al8   = (size_t)N * 8 * 4;
    size_t sz_count = (size_t)N * 4;
    size_t sz_offs  = (size_t)(N + 4) * 4;
    size_t sz_srcs  = (size_t)ET * 4;
    size_t sz_w     = (size_t)ET * 8 * 4;
    size_t required = sz_xb + sz_h1b + sz_aggA + sz_aggB + sz_wc + 2 * sz_vsd +
                      2 * sz_al8 + 2 * sz_count + sz_offs + 2 * sz_srcs + sz_w;
    if (ws_size < required) return;

    char* w = (char*)d_ws;
    u16* xb = (u16*)w;        w += sz_xb;
    u16* h1b = (u16*)w;       w += sz_h1b;
    u16* aggA = (u16*)w;      w += sz_aggA;
    u16* aggB = (u16*)w;      w += sz_aggB;
    u16* Wf = (u16*)w;        w += sz_wc;
    u16* vsdA = (u16*)w;      w += sz_vsd;
    u16* vsdB = (u16*)w;      w += sz_vsd;
    float* als = (float*)w;   w += sz_al8;
    float* ald = (float*)w;   w += sz_al8;
    int* count = (int*)w;     w += sz_count;
    int* cursor = (int*)w;    w += sz_count;
    int* offs = (int*)w;      w += sz_offs;
    int* srcs = (int*)w;      w += sz_srcs;
    int* dsts = (int*)w;      w += sz_srcs;
    float* wgt = (float*)w;   w += sz_w;
    float* out = (float*)d_out;

    hipMemsetAsync(count, 0, sz_count, stream);
    hist_kernel<<<512, 256, 0, stream>>>(ei, E, N, count);
    scan_kernel<<<1, 1024, 0, stream>>>(count, offs, cursor, N);
    scatter_kernel<<<512, 256, 0, stream>>>(ei, E, N, cursor, srcs, dsts);

    cvt_w_kernel<<<96, 256, 0, stream>>>(W1, Wr, W2, Wf);
    wvec_kernel<<<dim3(12, 4), 256, 0, stream>>>(W1, as1, ad1, Wr, asr, adr,
                                                 W2, as2, ad2, vsdA, vsdB);

    int nwb = (N + 3) / 4;
    int neb = (ET + 255) / 256;
    int gx = (N + 63) / 64;

    // group A: layer1 + residual (share the x gather)
    alA_kernel<<<gx, 256, 0, stream>>>(x, vsdA, xb, als, ald, N);
    ew_kernel<8><<<neb, 256, 0, stream>>>(als, ald, srcs, dsts, wgt, ET);
    aggx_kernel<8><<<nwb, 256, 0, stream>>>(xb, wgt, offs, srcs, aggA, N);
    gemmL1_kernel<<<dim3(gx, 2), 256, 0, stream>>>(aggA, Wf, b1, h1b, N);

    // group B: layer2 (+ fused residual GEMM at the end)
    alB_kernel<<<gx, 256, 0, stream>>>(h1b, vsdB, als, ald, N);
    ew_kernel<4><<<neb, 256, 0, stream>>>(als, ald, srcs, dsts, wgt, ET);
    aggx_kernel<4><<<nwb, 256, 0, stream>>>(h1b, wgt, offs, srcs, aggB, N);
    gemmF_kernel<<<dim3(gx, 2), 256, 0, stream>>>(aggB, aggA, Wf, b2, br, out, N);
}